// Round 2
// baseline (137.793 us; speedup 1.0000x reference)
//
#include <hip/hip_runtime.h>
#include <hip/hip_bf16.h>
#include <stdint.h>

// Problem constants (fixed by setup_inputs): B=2, C=256, H=W=64, dg=4, K=3x3.
#define HW   4096
#define NB   2

typedef float f32x4 __attribute__((ext_vector_type(4)));
typedef short s16x8 __attribute__((ext_vector_type(8)));

__device__ __forceinline__ unsigned short f2bf(float f) {
    // round-to-nearest-even f32 -> bf16 (bit twiddle; inputs are normal floats)
    union { float f; unsigned int u; } v; v.f = f;
    unsigned int u = v.u;
    unsigned int r = (u + 0x7FFFu + ((u >> 16) & 1u)) >> 16;
    return (unsigned short)r;
}

// ---------------------------------------------------------------------------
// K1: offset 1x1 conv + bilinear setup.
// loc = ((b*9+k)*4+g)*4096 + p ; stores 4 corner weights (validity folded) and
// 4 clipped row BYTE offsets into the f32 NHWC feature slice (row = 256*4 B).
// ---------------------------------------------------------------------------
__global__ void k_params(const float* __restrict__ pred, const float* __restrict__ wo,
                         float4* __restrict__ wbuf, int4* __restrict__ ibuf) {
    int loc = blockIdx.x * 256 + threadIdx.x;      // [0, 2*9*4*4096)
    int p  = loc & 4095;
    int g  = (loc >> 12) & 3;
    int bk = loc >> 14;                            // b*9 + k
    int b  = bk / 9;
    int k  = bk - b * 9;
    int rowy = ((g * 9 + k) * 2) * 34;             // offset channel (g,k,{y,x})
    float oy = 0.f, ox = 0.f;
    const float* pb = pred + (size_t)b * 34 * HW + p;
    #pragma unroll
    for (int c = 0; c < 34; ++c) {
        float pv = pb[c * HW];
        oy += wo[rowy + c]      * pv;
        ox += wo[rowy + 34 + c] * pv;
    }
    int h = p >> 6, w = p & 63;
    int ky = k / 3, kx = k - ky * 3;
    float py = oy + (float)(h + ky - 1);
    float px = ox + (float)(w + kx - 1);
    float fy0 = floorf(py), fx0 = floorf(px);
    int y0 = (int)fy0, x0 = (int)fx0;
    float fy = py - fy0, fx = px - fx0;
    float wy0 = 1.f - fy, wy1 = fy, wx0 = 1.f - fx, wx1 = fx;
    if (!(y0 >= 0  && y0 <= 63)) wy0 = 0.f;        // corner validity -> zero weight
    if (!(y0 >= -1 && y0 <= 62)) wy1 = 0.f;
    if (!(x0 >= 0  && x0 <= 63)) wx0 = 0.f;
    if (!(x0 >= -1 && x0 <= 62)) wx1 = 0.f;
    int cy0 = min(max(y0, 0), 63),     cy1 = min(max(y0 + 1, 0), 63);
    int cx0 = min(max(x0, 0), 63),     cx1 = min(max(x0 + 1, 0), 63);
    wbuf[loc] = make_float4(wy0 * wx0, wy0 * wx1, wy1 * wx0, wy1 * wx1);
    ibuf[loc] = make_int4((cy0 * 64 + cx0) << 10, (cy0 * 64 + cx1) << 10,
                          (cy1 * 64 + cx0) << 10, (cy1 * 64 + cx1) << 10);
}

// ---------------------------------------------------------------------------
// K2: NCHW f32 -> NHWC f32 for both feature maps. fbuf[((cv*2+b)*4096+p)*256+c]
// ---------------------------------------------------------------------------
__global__ void k_nhwc(const float* __restrict__ regf, const float* __restrict__ clsf,
                       float* __restrict__ fbuf) {
    __shared__ float tile[64][65];
    int bid = blockIdx.x;
    int pt = bid & 63;
    int cb = (bid >> 6) & 3;
    int b  = (bid >> 8) & 1;
    int cv = bid >> 9;
    const float* src = cv ? clsf : regf;
    int t = threadIdx.x;
    int pl = t & 63, q = t >> 6;
    #pragma unroll
    for (int i = 0; i < 16; ++i) {
        int cl = q + i * 4;
        tile[cl][pl] = src[((size_t)(b * 256 + cb * 64 + cl)) * HW + pt * 64 + pl];
    }
    __syncthreads();
    #pragma unroll
    for (int i = 0; i < 16; ++i) {
        int pl2 = q + i * 4;
        fbuf[((size_t)((cv * 2 + b) * HW + pt * 64 + pl2)) * 256 + cb * 64 + pl]
            = tile[pl][pl2];
    }
}

// ---------------------------------------------------------------------------
// K3: weights -> bf16 MFMA A-fragment order.
// flat index L = conv*73728 + ((s*2+kk)*16+ot)*64+lane ; element j:
//   o = ot*16 + (lane&15), c = kk*32 + (lane>>4)*8 + j, (k,g) = (s>>2, s&3)
// ---------------------------------------------------------------------------
__global__ void k_wfrag(const float* __restrict__ wr, const float* __restrict__ wc,
                        unsigned short* __restrict__ wfrag) {
    int L = blockIdx.x * 256 + threadIdx.x;        // [0, 2*73728)
    int conv = L / 73728;
    int r = L - conv * 73728;
    int lane = r & 63;
    int ot = (r >> 6) & 15;
    int kk = (r >> 10) & 1;
    int s  = r >> 11;                              // 0..35
    int k = s >> 2, g = s & 3;
    int o  = ot * 16 + (lane & 15);
    int cb = kk * 32 + (lane >> 4) * 8;
    const float* w = conv ? wc : wr;
    s16x8 v;
    #pragma unroll
    for (int j = 0; j < 8; ++j) {
        int c = cb + j;
        v[j] = (short)f2bf(w[((size_t)o * 256 + g * 64 + c) * 9 + k]);
    }
    *(s16x8*)(wfrag + (size_t)L * 8) = v;
}

// ---------------------------------------------------------------------------
// K4: fused implicit GEMM. Block = (conv,b,64-pixel tile) x 256 Cout.
// 512 threads = 8 waves (wave grid 4 o x 2 p, wave tile 64o x 32p).
// 36 K-steps of 64 (one (k,g) each): build sampled V tile -> LDS, then MFMA.
// ---------------------------------------------------------------------------
__global__ void __launch_bounds__(512)
k_main(const float4* __restrict__ wbuf, const int4* __restrict__ ibuf,
       const float* __restrict__ fbuf, const unsigned short* __restrict__ wfrag,
       float* __restrict__ out) {
    __shared__ __align__(16) unsigned short vt[2][64][72];   // 64 px x 64 ch + 16B pad

    int bid0 = blockIdx.x;
    int bid = (bid0 & 7) * 32 + (bid0 >> 3);       // XCD-contiguous swizzle (256%8==0)
    int conv = bid >> 7;
    int b    = (bid >> 6) & 1;
    int pt   = bid & 63;
    int p0   = pt * 64;

    int tid  = threadIdx.x;
    int lane = tid & 63;
    int wv   = tid >> 6;
    int wo   = wv >> 1, wp = wv & 1;
    int pl   = tid & 63;                           // build: pixel
    int cg   = tid >> 6;                           // build: channel group (8 ch)

    const char* fb = (const char*)(fbuf + (size_t)(conv * 2 + b) * HW * 256) + cg * 32;
    const unsigned short* wfc = wfrag + (size_t)conv * 73728 * 8;

    f32x4 acc[4][2];
    #pragma unroll
    for (int i = 0; i < 4; ++i)
        #pragma unroll
        for (int j = 0; j < 2; ++j)
            acc[i][j] = (f32x4){0.f, 0.f, 0.f, 0.f};

    auto build = [&](int s) {
        int k = s >> 2, g = s & 3;
        // FIX (round 1): group g samples channels g*64 + [0,64) -> +g*256 bytes
        const char* fbs = fb + g * 256;
        int pidx = ((b * 9 + k) * 4 + g) * HW + p0 + pl;
        float4 w4 = wbuf[pidx];
        int4   io = ibuf[pidx];
        f32x4 a0 = *(const f32x4*)(fbs + io.x);
        f32x4 a1 = *(const f32x4*)(fbs + io.x + 16);
        f32x4 b0 = *(const f32x4*)(fbs + io.y);
        f32x4 b1 = *(const f32x4*)(fbs + io.y + 16);
        f32x4 c0 = *(const f32x4*)(fbs + io.z);
        f32x4 c1 = *(const f32x4*)(fbs + io.z + 16);
        f32x4 d0 = *(const f32x4*)(fbs + io.w);
        f32x4 d1 = *(const f32x4*)(fbs + io.w + 16);
        f32x4 rlo = w4.x * a0 + w4.y * b0 + w4.z * c0 + w4.w * d0;
        f32x4 rhi = w4.x * a1 + w4.y * b1 + w4.z * c1 + w4.w * d1;
        s16x8 pk;
        pk[0] = (short)f2bf(rlo[0]); pk[1] = (short)f2bf(rlo[1]);
        pk[2] = (short)f2bf(rlo[2]); pk[3] = (short)f2bf(rlo[3]);
        pk[4] = (short)f2bf(rhi[0]); pk[5] = (short)f2bf(rhi[1]);
        pk[6] = (short)f2bf(rhi[2]); pk[7] = (short)f2bf(rhi[3]);
        *(s16x8*)&vt[s & 1][pl][cg * 8] = pk;
    };

    auto domfma = [&](int s) {
        const unsigned short* wfs = wfc + (size_t)s * 2048 * 8;
        #pragma unroll
        for (int kk = 0; kk < 2; ++kk) {
            s16x8 bfr[2];
            #pragma unroll
            for (int np = 0; np < 2; ++np) {
                const unsigned short* bsrc =
                    &vt[s & 1][wp * 32 + np * 16 + (lane & 15)][kk * 32 + (lane >> 4) * 8];
                bfr[np] = *(const s16x8*)bsrc;
            }
            #pragma unroll
            for (int mo = 0; mo < 4; ++mo) {
                const unsigned short* asrc =
                    wfs + ((size_t)(kk * 16 + wo * 4 + mo) * 64 + lane) * 8;
                s16x8 afr = *(const s16x8*)asrc;
                #pragma unroll
                for (int np = 0; np < 2; ++np)
                    acc[mo][np] = __builtin_amdgcn_mfma_f32_16x16x32_bf16(
                        afr, bfr[np], acc[mo][np], 0, 0, 0);
            }
        }
    };

    build(0);
    for (int s = 0; s < 36; ++s) {
        __syncthreads();           // all writes of vt[s&1] visible
        domfma(s);
        if (s < 35) build(s + 1);  // writes other buffer: no second barrier needed
    }

    // epilogue: C/D layout col = lane&15 (pixel), row = (lane>>4)*4 + reg (o)
    float* ob = out + (size_t)conv * (NB * 256 * HW) + (size_t)b * 256 * HW;
    #pragma unroll
    for (int mo = 0; mo < 4; ++mo)
        #pragma unroll
        for (int np = 0; np < 2; ++np)
            #pragma unroll
            for (int r = 0; r < 4; ++r) {
                int o = wo * 64 + mo * 16 + (lane >> 4) * 4 + r;
                int p = p0 + wp * 32 + np * 16 + (lane & 15);
                float v = acc[mo][np][r];
                ob[(size_t)o * HW + p] = v > 0.f ? v : 0.f;
            }
}

// ---------------------------------------------------------------------------
// ws layout (bytes):
//   [0,        4718592)  wbuf  : 294912 float4
//   [4718592,  9437184)  ibuf  : 294912 int4
//   [9437184, 26214400)  fbuf  : 4*4096*256 f32 NHWC
//   [26214400,28573696)  wfrag : 2*73728*8 bf16
// requires ws_size >= 28573696
// ---------------------------------------------------------------------------
extern "C" void kernel_launch(void* const* d_in, const int* in_sizes, int n_in,
                              void* d_out, int out_size, void* d_ws, size_t ws_size,
                              hipStream_t stream) {
    (void)in_sizes; (void)n_in; (void)out_size; (void)ws_size;
    const float* reg_feat = (const float*)d_in[0];
    const float* cls_feat = (const float*)d_in[1];
    const float* pred     = (const float*)d_in[2];
    const float* w_off    = (const float*)d_in[3];
    const float* w_reg    = (const float*)d_in[4];
    const float* w_cls    = (const float*)d_in[5];
    float* out = (float*)d_out;
    char* ws = (char*)d_ws;
    float4*         wbuf  = (float4*)ws;
    int4*           ibuf  = (int4*)(ws + 4718592);
    float*          fbuf  = (float*)(ws + 9437184);
    unsigned short* wfrag = (unsigned short*)(ws + 26214400);

    k_params<<<1152, 256, 0, stream>>>(pred, w_off, wbuf, ibuf);
    k_nhwc  <<<1024, 256, 0, stream>>>(reg_feat, cls_feat, fbuf);
    k_wfrag <<< 576, 256, 0, stream>>>(w_reg, w_cls, wfrag);
    k_main  <<< 256, 512, 0, stream>>>(wbuf, ibuf, fbuf, wfrag, out);
}

// Round 3
// 95.155 us; speedup vs baseline: 1.4481x; 1.4481x over previous
//
#include <hip/hip_runtime.h>
#include <hip/hip_bf16.h>
#include <stdint.h>

// Problem constants (fixed by setup_inputs): B=2, C=256, H=W=64, dg=4, K=3x3.
#define HW   4096
#define NB   2

typedef float f32x4 __attribute__((ext_vector_type(4)));
typedef short s16x8 __attribute__((ext_vector_type(8)));

__device__ __forceinline__ unsigned short f2bf(float f) {
    // round-to-nearest-even f32 -> bf16
    union { float f; unsigned int u; } v; v.f = f;
    unsigned int u = v.u;
    unsigned int r = (u + 0x7FFFu + ((u >> 16) & 1u)) >> 16;
    return (unsigned short)r;
}

__device__ __forceinline__ float bf2f(unsigned short u) {
    union { unsigned int u; float f; } v; v.u = ((unsigned int)u) << 16;
    return v.f;
}

// ---------------------------------------------------------------------------
// K1: offset 1x1 conv + bilinear setup.
// loc = ((b*9+k)*4+g)*4096 + p ; stores 4 corner weights (validity folded) and
// 4 clipped row BYTE offsets into the bf16 NHWC feature slice (row = 256*2 B).
// ---------------------------------------------------------------------------
__global__ void k_params(const float* __restrict__ pred, const float* __restrict__ wo,
                         float4* __restrict__ wbuf, int4* __restrict__ ibuf) {
    int loc = blockIdx.x * 256 + threadIdx.x;      // [0, 2*9*4*4096)
    int p  = loc & 4095;
    int g  = (loc >> 12) & 3;
    int bk = loc >> 14;                            // b*9 + k
    int b  = bk / 9;
    int k  = bk - b * 9;
    int rowy = ((g * 9 + k) * 2) * 34;             // offset channel (g,k,{y,x})
    float oy = 0.f, ox = 0.f;
    const float* pb = pred + (size_t)b * 34 * HW + p;
    #pragma unroll
    for (int c = 0; c < 34; ++c) {
        float pv = pb[c * HW];
        oy += wo[rowy + c]      * pv;
        ox += wo[rowy + 34 + c] * pv;
    }
    int h = p >> 6, w = p & 63;
    int ky = k / 3, kx = k - ky * 3;
    float py = oy + (float)(h + ky - 1);
    float px = ox + (float)(w + kx - 1);
    float fy0 = floorf(py), fx0 = floorf(px);
    int y0 = (int)fy0, x0 = (int)fx0;
    float fy = py - fy0, fx = px - fx0;
    float wy0 = 1.f - fy, wy1 = fy, wx0 = 1.f - fx, wx1 = fx;
    if (!(y0 >= 0  && y0 <= 63)) wy0 = 0.f;        // corner validity -> zero weight
    if (!(y0 >= -1 && y0 <= 62)) wy1 = 0.f;
    if (!(x0 >= 0  && x0 <= 63)) wx0 = 0.f;
    if (!(x0 >= -1 && x0 <= 62)) wx1 = 0.f;
    int cy0 = min(max(y0, 0), 63),     cy1 = min(max(y0 + 1, 0), 63);
    int cx0 = min(max(x0, 0), 63),     cx1 = min(max(x0 + 1, 0), 63);
    wbuf[loc] = make_float4(wy0 * wx0, wy0 * wx1, wy1 * wx0, wy1 * wx1);
    ibuf[loc] = make_int4((cy0 * 64 + cx0) << 9, (cy0 * 64 + cx1) << 9,
                          (cy1 * 64 + cx0) << 9, (cy1 * 64 + cx1) << 9);
}

// ---------------------------------------------------------------------------
// K2: NCHW f32 -> NHWC bf16 for both feature maps.
// fbuf[((cv*2+b)*4096+p)*256 + c] (ushort)
// ---------------------------------------------------------------------------
__global__ void k_nhwc(const float* __restrict__ regf, const float* __restrict__ clsf,
                       unsigned short* __restrict__ fbuf) {
    __shared__ float tile[64][65];
    int bid = blockIdx.x;
    int pt = bid & 63;
    int cb = (bid >> 6) & 3;
    int b  = (bid >> 8) & 1;
    int cv = bid >> 9;
    const float* src = cv ? clsf : regf;
    int t = threadIdx.x;
    int pl = t & 63, q = t >> 6;
    #pragma unroll
    for (int i = 0; i < 16; ++i) {
        int cl = q + i * 4;
        tile[cl][pl] = src[((size_t)(b * 256 + cb * 64 + cl)) * HW + pt * 64 + pl];
    }
    __syncthreads();
    int cpair = t & 31, prow = t >> 5;
    #pragma unroll
    for (int i = 0; i < 8; ++i) {
        int p = i * 8 + prow;
        unsigned int u0 = f2bf(tile[cpair * 2][p]);
        unsigned int u1 = f2bf(tile[cpair * 2 + 1][p]);
        *(unsigned int*)&fbuf[((size_t)((cv * 2 + b) * HW + pt * 64 + p)) * 256
                              + cb * 64 + cpair * 2] = u0 | (u1 << 16);
    }
}

// ---------------------------------------------------------------------------
// K3: weights -> bf16 MFMA A-fragment order.
// flat index L = conv*73728 + ((s*2+kk)*16+ot)*64+lane ; element j:
//   o = ot*16 + (lane&15), c = kk*32 + (lane>>4)*8 + j, (k,g) = (s>>2, s&3)
// ---------------------------------------------------------------------------
__global__ void k_wfrag(const float* __restrict__ wr, const float* __restrict__ wc,
                        unsigned short* __restrict__ wfrag) {
    int L = blockIdx.x * 256 + threadIdx.x;        // [0, 2*73728)
    int conv = L / 73728;
    int r = L - conv * 73728;
    int lane = r & 63;
    int ot = (r >> 6) & 15;
    int kk = (r >> 10) & 1;
    int s  = r >> 11;                              // 0..35
    int k = s >> 2, g = s & 3;
    int o  = ot * 16 + (lane & 15);
    int cb = kk * 32 + (lane >> 4) * 8;
    const float* w = conv ? wc : wr;
    s16x8 v;
    #pragma unroll
    for (int j = 0; j < 8; ++j) {
        int c = cb + j;
        v[j] = (short)f2bf(w[((size_t)o * 256 + g * 64 + c) * 9 + k]);
    }
    *(s16x8*)(wfrag + (size_t)L * 8) = v;
}

// ---------------------------------------------------------------------------
// K4: fused implicit GEMM. Block = (conv,b,64-pixel tile) x 256 Cout.
// 512 threads = 8 waves; wave wo covers 32 Cout x 64 px (acc[2][4]).
// Build lanes: px = tid>>3, cg = tid&7 -> per (pixel,corner) 8 lanes read a
// CONTIGUOUS 128B channel block (2 cache lines, was 8).
// Pipeline: gathers(s+1)+params(s+2) issued before a raw s_barrier (only
// lgkmcnt drained -> vmcnt stays in flight); MFMA(s); then lerp/pack/write(s+1).
// ---------------------------------------------------------------------------
__global__ void __launch_bounds__(512)
k_main(const float4* __restrict__ wbuf, const int4* __restrict__ ibuf,
       const unsigned short* __restrict__ fbuf, const unsigned short* __restrict__ wfrag,
       float* __restrict__ out) {
    __shared__ __align__(16) unsigned short vt[2][64][72];   // 64 px x 64 ch + pad

    int bid0 = blockIdx.x;
    int bid = (bid0 & 7) * 32 + (bid0 >> 3);       // XCD-contiguous swizzle (256%8==0)
    int conv = bid >> 7;
    int b    = (bid >> 6) & 1;
    int pt   = bid & 63;
    int p0   = pt * 64;

    int tid  = threadIdx.x;
    int lane = tid & 63;
    int wo   = tid >> 6;                           // wave id = Cout group (8 x 32)
    int px   = tid >> 3;                           // build: pixel 0..63
    int cg   = tid & 7;                            // build: channel granule (8 ch)

    const char* fbb = (const char*)(fbuf + (size_t)(conv * 2 + b) * HW * 256);
    const unsigned short* wfc = wfrag + (size_t)conv * 73728 * 8;

    f32x4 acc[2][4];
    #pragma unroll
    for (int i = 0; i < 2; ++i)
        #pragma unroll
        for (int j = 0; j < 4; ++j)
            acc[i][j] = (f32x4){0.f, 0.f, 0.f, 0.f};

    struct Par { float4 w4; int4 io; };
    struct Gat { s16x8 a, b, c, d; };

    auto ldpar = [&](int s) -> Par {
        int k = s >> 2, g = s & 3;
        int pidx = ((b * 9 + k) * 4 + g) * HW + p0 + px;
        Par P; P.w4 = wbuf[pidx]; P.io = ibuf[pidx];
        return P;
    };

    auto gather = [&](const Par& P, int g) -> Gat {
        const char* base = fbb + g * 128 + cg * 16;
        Gat G;
        G.a = *(const s16x8*)(base + P.io.x);
        G.b = *(const s16x8*)(base + P.io.y);
        G.c = *(const s16x8*)(base + P.io.z);
        G.d = *(const s16x8*)(base + P.io.w);
        return G;
    };

    auto finish = [&](const Par& P, const Gat& G, int buf) {
        float r[8];
        #pragma unroll
        for (int j = 0; j < 8; ++j) {
            r[j] = P.w4.x * bf2f((unsigned short)G.a[j])
                 + P.w4.y * bf2f((unsigned short)G.b[j])
                 + P.w4.z * bf2f((unsigned short)G.c[j])
                 + P.w4.w * bf2f((unsigned short)G.d[j]);
        }
        s16x8 pk;
        #pragma unroll
        for (int j = 0; j < 8; ++j) pk[j] = (short)f2bf(r[j]);
        *(s16x8*)&vt[buf][px][cg * 8] = pk;
    };

    auto domfma = [&](int s) {
        const unsigned short* wfs = wfc + (size_t)s * 2048 * 8;
        #pragma unroll
        for (int kk = 0; kk < 2; ++kk) {
            s16x8 bfr[4];
            #pragma unroll
            for (int np = 0; np < 4; ++np)
                bfr[np] = *(const s16x8*)
                    &vt[s & 1][np * 16 + (lane & 15)][kk * 32 + (lane >> 4) * 8];
            #pragma unroll
            for (int mo = 0; mo < 2; ++mo) {
                s16x8 afr = *(const s16x8*)
                    (wfs + ((size_t)(kk * 16 + wo * 2 + mo) * 64 + lane) * 8);
                #pragma unroll
                for (int np = 0; np < 4; ++np)
                    acc[mo][np] = __builtin_amdgcn_mfma_f32_16x16x32_bf16(
                        afr, bfr[np], acc[mo][np], 0, 0, 0);
            }
        }
    };

    // ---- software pipeline ----
    Par pc = ldpar(0);
    Par pn = ldpar(1);
    Gat gc = gather(pc, 0);
    finish(pc, gc, 0);                  // vt[0]

    for (int s = 0; s < 36; ++s) {
        Gat gn;
        Par p2 = pn;
        bool hasn = (s + 1 < 36);
        if (hasn)        gn = gather(pn, (s + 1) & 3);   // in flight across barrier
        if (s + 2 < 36)  p2 = ldpar(s + 2);
        asm volatile("s_waitcnt lgkmcnt(0)" ::: "memory"); // LDS writes visible
        __builtin_amdgcn_s_barrier();                      // vmcnt NOT drained
        domfma(s);
        if (hasn) finish(pn, gn, (s + 1) & 1);
        pn = p2;
    }

    // epilogue: C/D layout col = lane&15 (pixel), row = (lane>>4)*4 + reg (o)
    float* ob = out + (size_t)conv * (NB * 256 * HW) + (size_t)b * 256 * HW;
    #pragma unroll
    for (int mo = 0; mo < 2; ++mo)
        #pragma unroll
        for (int np = 0; np < 4; ++np)
            #pragma unroll
            for (int r = 0; r < 4; ++r) {
                int o = wo * 32 + mo * 16 + (lane >> 4) * 4 + r;
                int p = p0 + np * 16 + (lane & 15);
                float v = acc[mo][np][r];
                ob[(size_t)o * HW + p] = v > 0.f ? v : 0.f;
            }
}

// ---------------------------------------------------------------------------
// ws layout (bytes):
//   [0,        4718592)  wbuf  : 294912 float4
//   [4718592,  9437184)  ibuf  : 294912 int4
//   [9437184, 17825792)  fbuf  : 4*4096*256 bf16 NHWC
//   [17825792,20185088)  wfrag : 2*73728*8 bf16
// requires ws_size >= 20185088
// ---------------------------------------------------------------------------
extern "C" void kernel_launch(void* const* d_in, const int* in_sizes, int n_in,
                              void* d_out, int out_size, void* d_ws, size_t ws_size,
                              hipStream_t stream) {
    (void)in_sizes; (void)n_in; (void)out_size; (void)ws_size;
    const float* reg_feat = (const float*)d_in[0];
    const float* cls_feat = (const float*)d_in[1];
    const float* pred     = (const float*)d_in[2];
    const float* w_off    = (const float*)d_in[3];
    const float* w_reg    = (const float*)d_in[4];
    const float* w_cls    = (const float*)d_in[5];
    float* out = (float*)d_out;
    char* ws = (char*)d_ws;
    float4*         wbuf  = (float4*)ws;
    int4*           ibuf  = (int4*)(ws + 4718592);
    unsigned short* fbuf  = (unsigned short*)(ws + 9437184);
    unsigned short* wfrag = (unsigned short*)(ws + 17825792);

    k_params<<<1152, 256, 0, stream>>>(pred, w_off, wbuf, ibuf);
    k_nhwc  <<<1024, 256, 0, stream>>>(reg_feat, cls_feat, fbuf);
    k_wfrag <<< 576, 256, 0, stream>>>(w_reg, w_cls, wfrag);
    k_main  <<< 256, 512, 0, stream>>>(wbuf, ibuf, fbuf, wfrag, out);
}